// Round 11
// baseline (30.730 us; speedup 1.0000x reference)
//
#include <hip/hip_runtime.h>

// CountHistogram: B=128, C=4, Q=32, D=2048, NBINS=30
// out[b,c,q,bin] = sum_d [ bin(simmat[b,c,q,d]) == bin ] * (dtoks[b,d]!=-1) * (qtoks[b,q]!=-1)
//
// R10 = ABLATION PROBE (R4 + doubled LDS-atomic traffic into shadow histogram).
//   Purpose: measure DS-atomic pipe headroom. Shadow atomics use the SAME bin
//   indices -> identical conflict statistics -> exactly 2x representative load.
//   Shadow kept live vs DCE by an asm-consumed read (runtime bin indices make
//   the atomics non-provably-dead). Output path identical to R4.
//   Decision rule: dur >= ~31.5 us -> DS-bound, attack atomic count next.
//                  dur <= ~29 us   -> DS slack, R4 is the stream floor.

#define NBINS   30
#define DIM     2048
#define QDIM    32
#define CDIM    4
#define BDIM    128
#define GSTRIDE 33                                   // words per group histogram
#define WSTRIDE (8 * GSTRIDE)                        // 264 words per wave

typedef float nfloat4 __attribute__((ext_vector_type(4)));
typedef int   nint4   __attribute__((ext_vector_type(4)));

__global__ __launch_bounds__(256) void CountHistogram_kernel(
    const float* __restrict__ simmat,
    const int*   __restrict__ dtoks,
    const int*   __restrict__ qtoks,
    float*       __restrict__ out)
{
    const int tid  = threadIdx.x;
    const int wave = tid >> 6;
    const int lane = tid & 63;
    const int row  = blockIdx.x * 4 + wave;          // = b*C*Q + c*Q + q
    const int q    = row & (QDIM - 1);
    const int b    = row >> 7;                       // / (C*Q)

    __shared__ int hs [4 * WSTRIDE];                 // real histograms
    __shared__ int hs2[4 * WSTRIDE];                 // shadow (probe) histograms
    int* hw  = hs  + wave * WSTRIDE;
    int* hw2 = hs2 + wave * WSTRIDE;
    // zero both (same-wave DS ordering protects later atomics)
    hw [lane] = 0; hw [lane + 64] = 0; hw [lane + 128] = 0; hw [lane + 192] = 0;
    hw2[lane] = 0; hw2[lane + 64] = 0; hw2[lane + 128] = 0; hw2[lane + 192] = 0;
    if (lane < WSTRIDE - 256) { hw[lane + 256] = 0; hw2[lane + 256] = 0; }

    const int qt = qtoks[b * QDIM + q];              // wave-uniform
    int* hg  = hw  + (lane >> 3) * GSTRIDE;
    int* hg2 = hw2 + (lane >> 3) * GSTRIDE;

    if (qt != -1) {
        const nfloat4* sm = (const nfloat4*)(simmat + (size_t)row * DIM);
        const nint4*   dt = (const nint4*)(dtoks  + (size_t)b   * DIM);
        #pragma unroll
        for (int j = 0; j < 8; ++j) {
            const nfloat4 s = __builtin_nontemporal_load(&sm[j * 64 + lane]);
            const nint4   t = dt[j * 64 + lane];
            // bit-exact: ((x+1.00001f)/2.0f)*29.0f == (x+1.00001f)*14.5f
            int b0 = (int)((s.x + 1.00001f) * 14.5f);
            int b1 = (int)((s.y + 1.00001f) * 14.5f);
            int b2 = (int)((s.z + 1.00001f) * 14.5f);
            int b3 = (int)((s.w + 1.00001f) * 14.5f);
            b0 = (t.x != -1) ? b0 : 31;
            b1 = (t.y != -1) ? b1 : 31;
            b2 = (t.z != -1) ? b2 : 31;
            b3 = (t.w != -1) ? b3 : 31;
            atomicAdd(&hg[b0], 1);
            atomicAdd(&hg[b1], 1);
            atomicAdd(&hg[b2], 1);
            atomicAdd(&hg[b3], 1);
            // ---- probe: doubled, identically-distributed atomic traffic ----
            atomicAdd(&hg2[b0], 1);
            atomicAdd(&hg2[b1], 1);
            atomicAdd(&hg2[b2], 1);
            atomicAdd(&hg2[b3], 1);
        }
    }

    // keep shadow atomics live (runtime-indexed -> not provably dead)
    {
        int dummy = hw2[lane & (WSTRIDE - 1) & 255];
        asm volatile("" :: "v"(dummy));
    }

    // same-wave DS ordering: atomics above complete before these reads
    if (lane < NBINS) {
        int sum = 0;
        #pragma unroll
        for (int g = 0; g < 8; ++g)
            sum += hw[g * GSTRIDE + lane];
        out[(size_t)row * NBINS + lane] = (float)sum;
    }
}

extern "C" void kernel_launch(void* const* d_in, const int* in_sizes, int n_in,
                              void* d_out, int out_size, void* d_ws, size_t ws_size,
                              hipStream_t stream) {
    const float* simmat = (const float*)d_in[0];
    // d_in[1] = dlens (unused by the reference)
    const int*   dtoks  = (const int*)d_in[2];
    const int*   qtoks  = (const int*)d_in[3];
    float*       out    = (float*)d_out;

    const int nrows = BDIM * CDIM * QDIM;            // 16384
    CountHistogram_kernel<<<nrows / 4, 256, 0, stream>>>(simmat, dtoks, qtoks, out);
}

// Round 12
// 27.648 us; speedup vs baseline: 1.1115x; 1.1115x over previous
//
#include <hip/hip_runtime.h>

// CountHistogram: B=128, C=4, Q=32, D=2048, NBINS=30
// out[b,c,q,bin] = sum_d [ bin(simmat[b,c,q,d]) == bin ] * (dtoks[b,d]!=-1) * (qtoks[b,q]!=-1)
//
// FINAL (R11 = R4, best of 10 rounds: 27.54 us).
//   - one wave per row, no barriers.
//   - 8 sub-histograms per wave (8-lane groups), stride 33 words:
//     bank(bin, g) = (bin + g) mod 32 -> cross-group conflict-free,
//     same-address collisions confined to 8 lanes (~2-way, free per m136).
//   - masked elements -> dead slot 31, unconditional ds_add (no exec churn).
//   - nontemporal simmat loads (vs cacheable: +0.9 us, R7 A/B).
//   - bit-exact fold: ((x+1.00001f)/2.0f)*29.0f == (x+1.00001f)*14.5f
//     (/2 exact; single rounding each form; absmax 0.0 on-device).
//   Evidence ledger: atomic-conflict shaping, multi-row/wave amortization,
//   L3 replay reuse, occupancy caps, dtoks traffic all exonerated (R2-R9);
//   R10 shadow-atomic probe bounds total atomic-side headroom at ~3 us with
//   no cheaper substitute (VALU replacements are 10x the cycles). Residual =
//   134 MB NT read stream at ~4.9 TB/s + exposed atomic tail ~= practical
//   roofline for this access pattern.

#define NBINS   30
#define DIM     2048
#define QDIM    32
#define CDIM    4
#define BDIM    128
#define GSTRIDE 33                                   // words per group histogram
#define WSTRIDE (8 * GSTRIDE)                        // 264 words per wave

typedef float nfloat4 __attribute__((ext_vector_type(4)));
typedef int   nint4   __attribute__((ext_vector_type(4)));

__global__ __launch_bounds__(256) void CountHistogram_kernel(
    const float* __restrict__ simmat,
    const int*   __restrict__ dtoks,
    const int*   __restrict__ qtoks,
    float*       __restrict__ out)
{
    const int tid  = threadIdx.x;
    const int wave = tid >> 6;
    const int lane = tid & 63;
    const int row  = blockIdx.x * 4 + wave;          // = b*C*Q + c*Q + q
    const int q    = row & (QDIM - 1);
    const int b    = row >> 7;                       // / (C*Q)

    __shared__ int hs[4 * WSTRIDE];                  // 4 waves * 8 groups * 33 words
    int* hw = hs + wave * WSTRIDE;
    // zero 264 words per wave (same-wave DS ordering protects later atomics)
    hw[lane] = 0; hw[lane + 64] = 0; hw[lane + 128] = 0; hw[lane + 192] = 0;
    if (lane < WSTRIDE - 256) hw[lane + 256] = 0;

    const int qt = qtoks[b * QDIM + q];              // wave-uniform
    int* hg = hw + (lane >> 3) * GSTRIDE;            // this lane's group histogram

    if (qt != -1) {
        const nfloat4* sm = (const nfloat4*)(simmat + (size_t)row * DIM);
        const nint4*   dt = (const nint4*)(dtoks  + (size_t)b   * DIM);
        #pragma unroll
        for (int j = 0; j < 8; ++j) {
            const nfloat4 s = __builtin_nontemporal_load(&sm[j * 64 + lane]);
            const nint4   t = dt[j * 64 + lane];
            // bit-exact: ((x+1.00001f)/2.0f)*29.0f == (x+1.00001f)*14.5f
            int b0 = (int)((s.x + 1.00001f) * 14.5f);
            int b1 = (int)((s.y + 1.00001f) * 14.5f);
            int b2 = (int)((s.z + 1.00001f) * 14.5f);
            int b3 = (int)((s.w + 1.00001f) * 14.5f);
            // masked elements -> dead slot 31 (bins 30..32 never read back)
            b0 = (t.x != -1) ? b0 : 31;
            b1 = (t.y != -1) ? b1 : 31;
            b2 = (t.z != -1) ? b2 : 31;
            b3 = (t.w != -1) ? b3 : 31;
            atomicAdd(&hg[b0], 1);
            atomicAdd(&hg[b1], 1);
            atomicAdd(&hg[b2], 1);
            atomicAdd(&hg[b3], 1);
        }
    }

    // same-wave DS ordering: atomics above complete before these reads
    if (lane < NBINS) {
        int sum = 0;
        #pragma unroll
        for (int g = 0; g < 8; ++g)
            sum += hw[g * GSTRIDE + lane];
        out[(size_t)row * NBINS + lane] = (float)sum;
    }
}

extern "C" void kernel_launch(void* const* d_in, const int* in_sizes, int n_in,
                              void* d_out, int out_size, void* d_ws, size_t ws_size,
                              hipStream_t stream) {
    const float* simmat = (const float*)d_in[0];
    // d_in[1] = dlens (unused by the reference)
    const int*   dtoks  = (const int*)d_in[2];
    const int*   qtoks  = (const int*)d_in[3];
    float*       out    = (float*)d_out;

    const int nrows = BDIM * CDIM * QDIM;            // 16384
    CountHistogram_kernel<<<nrows / 4, 256, 0, stream>>>(simmat, dtoks, qtoks, out);
}